// Round 3
// baseline (277.193 us; speedup 1.0000x reference)
//
#include <hip/hip_runtime.h>
#include <stdint.h>

typedef short bf16x8 __attribute__((ext_vector_type(8)));
typedef float f32x4 __attribute__((ext_vector_type(4)));
typedef unsigned short ushort_t;
typedef ushort_t ushort8 __attribute__((ext_vector_type(8)));

#define TOKENS 131072
#define DMODEL 128
#define DIN 160
#define DHID 512
#define NEXP 8
#define BEH 32
#define CAP 24576
#define MT 256
#define TILES (CAP / MT)   /* 96 */

// workspace layout (bytes)
#define OFF_COUNTS 0
#define OFF_LISTS  1024
#define OFF_WIP    (OFF_LISTS + NEXP*CAP*4)
#define OFF_WOP    (OFF_WIP + 8*32*5*64*8*2)

#define SCATTER_BLOCKS (TOKENS / 256)                /* 512 */
#define NWI (8*32*5*64)                              /* 81920 */
#define NWO (8*8*16*64)                              /* 65536 */
#define PACK_BLOCKS ((NWI + NWO + 255) / 256)        /* 576 */

__device__ __forceinline__ ushort_t f2b(float f) {
    union { float f; uint32_t u; } x; x.f = f;
    uint32_t r = x.u + 0x7FFF + ((x.u >> 16) & 1);   // RNE
    return (ushort_t)(r >> 16);
}

// pack two f32 -> two bf16 (round-half-up; error bound = 0.5 ulp, same as RNE)
__device__ __forceinline__ uint32_t pk2(float lo, float hi) {
    uint32_t a = __float_as_uint(lo) + 0x8000u;
    uint32_t b = __float_as_uint(hi) + 0x8000u;
    return (a >> 16) | (b & 0xFFFF0000u);
}

// ---------------- Phase A+B fused: scatter tokens + pack weights ----------------
__global__ __launch_bounds__(256) void prep_kernel(
    const int* __restrict__ pos, int* __restrict__ counts, int* __restrict__ lists,
    const float* __restrict__ Wi, const float* __restrict__ Wo,
    ushort_t* __restrict__ wiP, ushort_t* __restrict__ woP)
{
    __shared__ int lcnt[NEXP];
    __shared__ int lbase[NEXP];
    int tid = threadIdx.x;
    if (blockIdx.x < SCATTER_BLOCKS) {
        if (tid < NEXP) lcnt[tid] = 0;
        __syncthreads();
        int t = blockIdx.x * 256 + tid;
        int e = pos[t];
        int slot = atomicAdd(&lcnt[e], 1);
        __syncthreads();
        if (tid < NEXP) lbase[tid] = atomicAdd(&counts[tid], lcnt[tid]);
        __syncthreads();
        int p = lbase[e] + slot;
        if (p < CAP) lists[e * CAP + p] = t;
        return;
    }
    int idx = (blockIdx.x - SCATTER_BLOCKS) * 256 + tid;
    // fragment layout (operand-symmetric A/B): lane L holds W[k=(L>>4)*8+j][d16=L&15]
    if (idx < NWI) {
        int L = idx & 63; int r = idx >> 6;
        int s = r % 5; r /= 5;
        int t1 = r & 31; int e = r >> 5;
        int n = t1 * 16 + (L & 15);
        int kb = s * 32 + ((L >> 4) & 3) * 8;
        ushort8 o;
        #pragma unroll
        for (int j = 0; j < 8; ++j)
            o[j] = f2b(Wi[((size_t)e * DIN + kb + j) * DHID + n]);
        *(ushort8*)(wiP + (size_t)idx * 8) = o;
    } else {
        int i2 = idx - NWI;
        if (i2 >= NWO) return;
        int L = i2 & 63; int r = i2 >> 6;
        int ks = r & 15; r >>= 4;
        int t2 = r & 7; int e = r >> 3;
        int n = t2 * 16 + (L & 15);
        int kb = ks * 32 + ((L >> 4) & 3) * 8;
        ushort8 o;
        #pragma unroll
        for (int j = 0; j < 8; ++j)
            o[j] = f2b(Wo[((size_t)e * DHID + kb + j) * DMODEL + n]);
        *(ushort8*)(woP + (size_t)i2 * 8) = o;
    }
}

// ---------------- Phase C: per-expert fused MLP ----------------
// block = 256 tokens of one expert, 4 waves, wave owns 64 tokens (4 token-tiles).
// GEMM1 transposed (M=hid, N=tok) so h exits with tok=lane&15; shuffle-transpose
// (8 shfl + 4 sel) converts C-layout -> GEMM2 A-layout in-register. No barriers
// after x staging, no h LDS round-trip.
__global__ __launch_bounds__(256, 2) void expert_gemm(
    const float* __restrict__ hidden, const int* __restrict__ bindex,
    const int* __restrict__ lists, const int* __restrict__ counts,
    const ushort_t* __restrict__ wiP, const ushort_t* __restrict__ woP,
    const float* __restrict__ emb, float* __restrict__ out)
{
    int e = blockIdx.y;
    int tile = blockIdx.x;
    int count = counts[e]; if (count > CAP) count = CAP;
    int base = tile * MT;
    if (base >= count) return;
    int mvalid = count - base; if (mvalid > MT) mvalid = MT;

    // x pre-packed in B-fragment order: [tok-tile(16)][s(5)][lane(64)][8 bf16] = 80 KB
    __shared__ ushort_t xLds[16 * 5 * 64 * 8];

    int tid = threadIdx.x;
    const int* listE = lists + (size_t)e * CAP + base;

    // ---- stage x = bf16(concat(hidden[t], emb[bi])) into fragment layout ----
    #pragma unroll 1
    for (int it = 0; it < 20; ++it) {
        int idx = it * 256 + tid;            // 5120 granules of 8 elements
        unsigned r = (unsigned)idx / 20u;    // token slot 0..255
        int g = idx - (int)r * 20;           // granule 0..19 (k0 = g*8)
        ushort8 o;
        if ((int)r < mvalid) {
            int t = listE[r];
            int c0 = g * 8;
            const float* src;
            if (c0 < DMODEL) src = hidden + (size_t)t * DMODEL + c0;
            else             src = emb + (size_t)bindex[t] * BEH + (c0 - DMODEL);
            f32x4 p0 = *(const f32x4*)src;
            f32x4 p1 = *(const f32x4*)(src + 4);
            uint32_t d0 = pk2(p0[0], p0[1]), d1 = pk2(p0[2], p0[3]);
            uint32_t d2 = pk2(p1[0], p1[1]), d3 = pk2(p1[2], p1[3]);
            o = __builtin_bit_cast(ushort8, (uint4){d0, d1, d2, d3});
        } else {
            o = (ushort8)0;
        }
        // element (tok,k) -> [tok>>4][k>>5][((k>>3)&3)*16 + (tok&15)][k&7]
        int didx = (((int)(r >> 4) * 5 + (g >> 2)) * 64 + (g & 3) * 16 + (int)(r & 15)) * 8;
        *(ushort8*)&xLds[didx] = o;
    }
    __syncthreads();

    int lane = tid & 63;
    int w = tid >> 6;
    int l15 = lane & 15;
    int quad = lane >> 4;

    const ushort_t* wiPe = wiP + (size_t)e * 32 * 5 * 64 * 8;
    const ushort_t* woPe = woP + (size_t)e * 8 * 16 * 64 * 8;

    int srcA = (quad & 1) * 32 + l15;   // shuffle sources for layout transform
    int srcB = srcA + 16;
    int selM1 = quad >> 1;

    f32x4 yacc[4][8] = {};

    #pragma unroll 1
    for (int c = 0; c < 8; ++c) {            // 8 chunks of 64 hidden units
        #pragma unroll 1
        for (int p = 0; p < 2; ++p) {        // 2 k-steps (32 hid) per chunk
            int t1 = c * 4 + p * 2;          // hid16-tile pair {t1, t1+1}
            // GEMM1^T: hT[32 hid x 64 tok] = WiT-tiles @ x
            f32x4 hacc[2][4] = {};
            #pragma unroll
            for (int s = 0; s < 5; ++s) {
                bf16x8 a0 = *(const bf16x8*)(wiPe + (size_t)((t1 * 5 + s) * 64 + lane) * 8);
                bf16x8 a1 = *(const bf16x8*)(wiPe + (size_t)(((t1 + 1) * 5 + s) * 64 + lane) * 8);
                #pragma unroll
                for (int tt = 0; tt < 4; ++tt) {
                    bf16x8 xb = *(const bf16x8*)&xLds[(((w * 4 + tt) * 5 + s) * 64 + lane) * 8];
                    hacc[0][tt] = __builtin_amdgcn_mfma_f32_16x16x32_bf16(a0, xb, hacc[0][tt], 0, 0, 0);
                    hacc[1][tt] = __builtin_amdgcn_mfma_f32_16x16x32_bf16(a1, xb, hacc[1][tt], 0, 0, 0);
                }
            }
            // relu + pack + shuffle-transpose -> GEMM2 A-frags, then GEMM2
            int ks = c * 2 + p;
            #pragma unroll
            for (int tt = 0; tt < 4; ++tt) {
                f32x4 h0 = hacc[0][tt], h1 = hacc[1][tt];
                #pragma unroll
                for (int r = 0; r < 4; ++r) {
                    h0[r] = h0[r] > 0.f ? h0[r] : 0.f;
                    h1[r] = h1[r] > 0.f ? h1[r] : 0.f;
                }
                uint32_t p00 = pk2(h0[0], h0[1]), p01 = pk2(h0[2], h0[3]);
                uint32_t p10 = pk2(h1[0], h1[1]), p11 = pk2(h1[2], h1[3]);
                // dst lane (q,l15): j0-3 <- tile[q>>1] lane srcA, j4-7 <- lane srcB
                uint32_t a00 = (uint32_t)__shfl((int)p00, srcA);
                uint32_t a01 = (uint32_t)__shfl((int)p01, srcA);
                uint32_t a02 = (uint32_t)__shfl((int)p00, srcB);
                uint32_t a03 = (uint32_t)__shfl((int)p01, srcB);
                uint32_t a10 = (uint32_t)__shfl((int)p10, srcA);
                uint32_t a11 = (uint32_t)__shfl((int)p11, srcA);
                uint32_t a12 = (uint32_t)__shfl((int)p10, srcB);
                uint32_t a13 = (uint32_t)__shfl((int)p11, srcB);
                uint4 dv = { selM1 ? a10 : a00, selM1 ? a11 : a01,
                             selM1 ? a12 : a02, selM1 ? a13 : a03 };
                bf16x8 afrag = __builtin_bit_cast(bf16x8, dv);
                #pragma unroll
                for (int n = 0; n < 8; ++n) {
                    bf16x8 b = *(const bf16x8*)(woPe + (size_t)((n * 16 + ks) * 64 + lane) * 8);
                    yacc[tt][n] = __builtin_amdgcn_mfma_f32_16x16x32_bf16(afrag, b, yacc[tt][n], 0, 0, 0);
                }
            }
        }
    }

    // epilogue: yacc C-layout -> out[token][dmodel]
    #pragma unroll
    for (int tt = 0; tt < 4; ++tt)
        #pragma unroll
        for (int r = 0; r < 4; ++r) {
            int row = w * 64 + tt * 16 + quad * 4 + r;
            if (row < mvalid) {
                int tok = listE[row];
                float* dst = out + (size_t)tok * DMODEL + l15;
                #pragma unroll
                for (int n = 0; n < 8; ++n)
                    dst[n * 16] = yacc[tt][n][r];
            }
        }
}

extern "C" void kernel_launch(void* const* d_in, const int* in_sizes, int n_in,
                              void* d_out, int out_size, void* d_ws, size_t ws_size,
                              hipStream_t stream) {
    const float* hidden = (const float*)d_in[0];
    const int*   pos    = (const int*)d_in[1];
    const int*   beh    = (const int*)d_in[2];
    const float* Wi     = (const float*)d_in[3];
    const float* Wo     = (const float*)d_in[4];
    const float* emb    = (const float*)d_in[5];

    char* ws = (char*)d_ws;
    int* counts   = (int*)(ws + OFF_COUNTS);
    int* lists    = (int*)(ws + OFF_LISTS);
    ushort_t* wiP = (ushort_t*)(ws + OFF_WIP);
    ushort_t* woP = (ushort_t*)(ws + OFF_WOP);

    hipMemsetAsync(counts, 0, NEXP * sizeof(int), stream);
    prep_kernel<<<SCATTER_BLOCKS + PACK_BLOCKS, 256, 0, stream>>>(pos, counts, lists, Wi, Wo, wiP, woP);
    expert_gemm<<<dim3(TILES, NEXP), 256, 0, stream>>>(
        hidden, beh, lists, counts, wiP, woP, emb, (float*)d_out);
}

// Round 4
// 192.236 us; speedup vs baseline: 1.4419x; 1.4419x over previous
//
#include <hip/hip_runtime.h>
#include <stdint.h>

typedef short bf16x8 __attribute__((ext_vector_type(8)));
typedef float f32x4 __attribute__((ext_vector_type(4)));
typedef unsigned short ushort_t;
typedef ushort_t ushort8 __attribute__((ext_vector_type(8)));

#define TOKENS 131072
#define DMODEL 128
#define DIN 160
#define DHID 512
#define NEXP 8
#define BEH 32
#define CAP 24576
#define MT 128
#define TILES (CAP / MT)   /* 192 */

// workspace layout (bytes)
#define OFF_COUNTS 0
#define OFF_LISTS  1024
#define OFF_WIP    (OFF_LISTS + NEXP*CAP*4)
#define OFF_WOP    (OFF_WIP + 8*32*5*64*8*2)

#define SCATTER_BLOCKS (TOKENS / 256)                /* 512 */
#define NWI (8*32*5*64)                              /* 81920 */
#define NWO (8*8*16*64)                              /* 65536 */
#define PACK_BLOCKS ((NWI + NWO + 255) / 256)        /* 576 */

#define STEP_SHORTS 9216   /* 18 KB per step buffer: 5120 wi + 4096 wo (shorts) */

typedef const __attribute__((address_space(1))) uint32_t* gu32p;
typedef __attribute__((address_space(3))) uint32_t* lu32p;

__device__ __forceinline__ ushort_t f2b(float f) {
    union { float f; uint32_t u; } x; x.f = f;
    uint32_t r = x.u + 0x7FFF + ((x.u >> 16) & 1);   // RNE
    return (ushort_t)(r >> 16);
}

// pack two f32 -> two bf16 (round-half-up)
__device__ __forceinline__ uint32_t pk2(float lo, float hi) {
    uint32_t a = __float_as_uint(lo) + 0x8000u;
    uint32_t b = __float_as_uint(hi) + 0x8000u;
    return (a >> 16) | (b & 0xFFFF0000u);
}

// ---------------- Phase A+B fused: scatter tokens + pack weights ----------------
__global__ __launch_bounds__(256) void prep_kernel(
    const int* __restrict__ pos, int* __restrict__ counts, int* __restrict__ lists,
    const float* __restrict__ Wi, const float* __restrict__ Wo,
    ushort_t* __restrict__ wiP, ushort_t* __restrict__ woP)
{
    __shared__ int lcnt[NEXP];
    __shared__ int lbase[NEXP];
    int tid = threadIdx.x;
    if (blockIdx.x < SCATTER_BLOCKS) {
        if (tid < NEXP) lcnt[tid] = 0;
        __syncthreads();
        int t = blockIdx.x * 256 + tid;
        int e = pos[t];
        int slot = atomicAdd(&lcnt[e], 1);
        __syncthreads();
        if (tid < NEXP) lbase[tid] = atomicAdd(&counts[tid], lcnt[tid]);
        __syncthreads();
        int p = lbase[e] + slot;
        if (p < CAP) lists[e * CAP + p] = t;
        return;
    }
    int idx = (blockIdx.x - SCATTER_BLOCKS) * 256 + tid;
    // fragment layout (operand-symmetric): lane L holds W[k=(L>>4)*8+j][d16=L&15]
    if (idx < NWI) {
        int L = idx & 63; int r = idx >> 6;
        int s = r % 5; r /= 5;
        int t1 = r & 31; int e = r >> 5;
        int n = t1 * 16 + (L & 15);
        int kb = s * 32 + ((L >> 4) & 3) * 8;
        ushort8 o;
        #pragma unroll
        for (int j = 0; j < 8; ++j)
            o[j] = f2b(Wi[((size_t)e * DIN + kb + j) * DHID + n]);
        *(ushort8*)(wiP + (size_t)idx * 8) = o;
    } else {
        int i2 = idx - NWI;
        if (i2 >= NWO) return;
        int L = i2 & 63; int r = i2 >> 6;
        int ks = r & 15; r >>= 4;
        int t2 = r & 7; int e = r >> 3;
        int n = t2 * 16 + (L & 15);
        int kb = ks * 32 + ((L >> 4) & 3) * 8;
        ushort8 o;
        #pragma unroll
        for (int j = 0; j < 8; ++j)
            o[j] = f2b(Wo[((size_t)e * DHID + kb + j) * DMODEL + n]);
        *(ushort8*)(woP + (size_t)i2 * 8) = o;
    }
}

// async-stage one K-step's weight fragments (18 KB) into dstBuf.
// granules g: [0,640) = Wi (10 KB contiguous at step*10KB); [640,1152) = Wo,
// 8 regions of 1 KB at ((n*16+step)*64)*16 bytes. All branches wave-uniform.
__device__ __forceinline__ void stage_step(
    const ushort_t* __restrict__ wiPe, const ushort_t* __restrict__ woPe,
    ushort_t* dstBuf, int step, int tid)
{
    #pragma unroll
    for (int it = 0; it < 5; ++it) {
        int g = it * 256 + tid;
        if (it == 4 && tid >= 128) break;          // waves 2,3 skip (uniform)
        const ushort_t* src;
        if (g < 640) {
            src = wiPe + (size_t)step * 5120 + (size_t)g * 8;
        } else {
            int g2 = g - 640;
            src = woPe + ((size_t)(((g2 >> 6) * 16 + step) * 64 + (g2 & 63))) * 8;
        }
        __builtin_amdgcn_global_load_lds((gu32p)(const void*)src,
                                         (lu32p)(void*)(dstBuf + g * 8), 16, 0, 0);
    }
}

// x = concat(hidden[t], emb[bi]); 8 consecutive floats at col c0 (8-aligned)
__device__ __forceinline__ bf16x8 load_x8(const float* __restrict__ hidden,
                                          const float* __restrict__ emb,
                                          int t, int bi, int c0) {
    if (t < 0) return (bf16x8)0;
    const float* src = (c0 < DMODEL) ? (hidden + (size_t)t * DMODEL + c0)
                                     : (emb + (size_t)bi * BEH + (c0 - DMODEL));
    f32x4 p0 = *(const f32x4*)src;
    f32x4 p1 = *(const f32x4*)(src + 4);
    uint32_t d0 = pk2(p0[0], p0[1]), d1 = pk2(p0[2], p0[3]);
    uint32_t d2 = pk2(p1[0], p1[1]), d3 = pk2(p1[2], p1[3]);
    return __builtin_bit_cast(bf16x8, (uint4){d0, d1, d2, d3});
}

// ---------------- Phase C: per-expert fused MLP ----------------
// block = 128 tokens, 4 waves, wave owns 32 tokens (2 token-tiles).
// Weights staged per K-step into LDS (double-buffered, async global_load_lds);
// x in registers as B-frags; GEMM1 transposed; shuffle-transpose h -> GEMM2 A.
__global__ __launch_bounds__(256, 3) void expert_gemm(
    const float* __restrict__ hidden, const int* __restrict__ bindex,
    const int* __restrict__ lists, const int* __restrict__ counts,
    const ushort_t* __restrict__ wiP, const ushort_t* __restrict__ woP,
    const float* __restrict__ emb, float* __restrict__ out)
{
    int e = blockIdx.y;
    int tile = blockIdx.x;
    int count = counts[e]; if (count > CAP) count = CAP;
    int base = tile * MT;
    if (base >= count) return;
    int mvalid = count - base; if (mvalid > MT) mvalid = MT;

    __shared__ ushort_t wbuf[2][STEP_SHORTS];   // 36 KB

    int tid = threadIdx.x;
    int lane = tid & 63;
    int w = tid >> 6;
    int l15 = lane & 15;
    int quad = lane >> 4;

    const int* listE = lists + (size_t)e * CAP + base;
    const ushort_t* wiPe = wiP + (size_t)e * 32 * 5 * 64 * 8;
    const ushort_t* woPe = woP + (size_t)e * 8 * 16 * 64 * 8;

    // kick off step-0 weight staging before the x gather (overlap L2 latency)
    stage_step(wiPe, woPe, wbuf[0], 0, tid);

    // ---- x B-fragments in registers: lane holds x[k=s*32+quad*8+j][tok=base+tt*16+l15]
    bf16x8 xf[2][5];
    int tok[2], bi[2];
    #pragma unroll
    for (int tt = 0; tt < 2; ++tt) {
        int row = w * 32 + tt * 16 + l15;
        tok[tt] = -1; bi[tt] = 0;
        if (row < mvalid) { tok[tt] = listE[row]; bi[tt] = bindex[tok[tt]]; }
    }
    #pragma unroll
    for (int s = 0; s < 5; ++s) {
        int c0 = s * 32 + quad * 8;
        xf[0][s] = load_x8(hidden, emb, tok[0], bi[0], c0);
        xf[1][s] = load_x8(hidden, emb, tok[1], bi[1], c0);
    }

    int srcA = (quad & 1) * 32 + l15;   // shuffle sources for h layout transform
    int srcB = srcA + 16;
    int selM1 = quad >> 1;

    f32x4 yacc[2][8] = {};

    #pragma unroll 2
    for (int step = 0; step < 16; ++step) {     // 16 K-steps of 32 hidden units
        int cur = step & 1;
        __syncthreads();                        // wbuf[cur] staged (drains vmcnt)
        if (step + 1 < 16)
            stage_step(wiPe, woPe, wbuf[cur ^ 1], step + 1, tid);

        const ushort_t* wiS = wbuf[cur];            // [2 tiles][5 s][64][8]
        const ushort_t* woS = wbuf[cur] + 5120;     // [8 n][64][8]

        // GEMM1^T: hT[32 hid x 32 tok] = Wi-tiles @ x
        f32x4 hacc[2][2] = {};
        #pragma unroll
        for (int s = 0; s < 5; ++s) {
            bf16x8 a0 = *(const bf16x8*)&wiS[(0 * 5 + s) * 512 + lane * 8];
            bf16x8 a1 = *(const bf16x8*)&wiS[(1 * 5 + s) * 512 + lane * 8];
            #pragma unroll
            for (int tt = 0; tt < 2; ++tt) {
                hacc[0][tt] = __builtin_amdgcn_mfma_f32_16x16x32_bf16(a0, xf[tt][s], hacc[0][tt], 0, 0, 0);
                hacc[1][tt] = __builtin_amdgcn_mfma_f32_16x16x32_bf16(a1, xf[tt][s], hacc[1][tt], 0, 0, 0);
            }
        }
        // relu + pack + shuffle-transpose -> GEMM2 A-frags, then GEMM2
        #pragma unroll
        for (int tt = 0; tt < 2; ++tt) {
            f32x4 h0 = hacc[0][tt], h1 = hacc[1][tt];
            #pragma unroll
            for (int r = 0; r < 4; ++r) {
                h0[r] = h0[r] > 0.f ? h0[r] : 0.f;
                h1[r] = h1[r] > 0.f ? h1[r] : 0.f;
            }
            uint32_t p00 = pk2(h0[0], h0[1]), p01 = pk2(h0[2], h0[3]);
            uint32_t p10 = pk2(h1[0], h1[1]), p11 = pk2(h1[2], h1[3]);
            uint32_t a00 = (uint32_t)__shfl((int)p00, srcA);
            uint32_t a01 = (uint32_t)__shfl((int)p01, srcA);
            uint32_t a02 = (uint32_t)__shfl((int)p00, srcB);
            uint32_t a03 = (uint32_t)__shfl((int)p01, srcB);
            uint32_t a10 = (uint32_t)__shfl((int)p10, srcA);
            uint32_t a11 = (uint32_t)__shfl((int)p11, srcA);
            uint32_t a12 = (uint32_t)__shfl((int)p10, srcB);
            uint32_t a13 = (uint32_t)__shfl((int)p11, srcB);
            uint4 dv = { selM1 ? a10 : a00, selM1 ? a11 : a01,
                         selM1 ? a12 : a02, selM1 ? a13 : a03 };
            bf16x8 afrag = __builtin_bit_cast(bf16x8, dv);
            #pragma unroll
            for (int n = 0; n < 8; ++n) {
                bf16x8 b = *(const bf16x8*)&woS[(n * 64 + lane) * 8];
                yacc[tt][n] = __builtin_amdgcn_mfma_f32_16x16x32_bf16(afrag, b, yacc[tt][n], 0, 0, 0);
            }
        }
    }

    // epilogue: yacc C-layout -> out[token][dmodel]
    #pragma unroll
    for (int tt = 0; tt < 2; ++tt)
        #pragma unroll
        for (int r = 0; r < 4; ++r) {
            int row = w * 32 + tt * 16 + quad * 4 + r;
            if (row < mvalid) {
                int t = listE[row];
                float* dst = out + (size_t)t * DMODEL + l15;
                #pragma unroll
                for (int n = 0; n < 8; ++n)
                    dst[n * 16] = yacc[tt][n][r];
            }
        }
}

extern "C" void kernel_launch(void* const* d_in, const int* in_sizes, int n_in,
                              void* d_out, int out_size, void* d_ws, size_t ws_size,
                              hipStream_t stream) {
    const float* hidden = (const float*)d_in[0];
    const int*   pos    = (const int*)d_in[1];
    const int*   beh    = (const int*)d_in[2];
    const float* Wi     = (const float*)d_in[3];
    const float* Wo     = (const float*)d_in[4];
    const float* emb    = (const float*)d_in[5];

    char* ws = (char*)d_ws;
    int* counts   = (int*)(ws + OFF_COUNTS);
    int* lists    = (int*)(ws + OFF_LISTS);
    ushort_t* wiP = (ushort_t*)(ws + OFF_WIP);
    ushort_t* woP = (ushort_t*)(ws + OFF_WOP);

    hipMemsetAsync(counts, 0, NEXP * sizeof(int), stream);
    prep_kernel<<<SCATTER_BLOCKS + PACK_BLOCKS, 256, 0, stream>>>(pos, counts, lists, Wi, Wo, wiP, woP);
    expert_gemm<<<dim3(TILES, NEXP), 256, 0, stream>>>(
        hidden, beh, lists, counts, wiP, woP, emb, (float*)d_out);
}